// Round 1
// baseline (1626.173 us; speedup 1.0000x reference)
//
#include <hip/hip_runtime.h>

#define N_NODES 50000
#define N_EDGES 800000
#define N_GRAPHS 64

// ---------------- degree / norm ----------------

__global__ void k_init_deg(float* deg) {
    int i = blockIdx.x * blockDim.x + threadIdx.x;
    if (i < N_NODES) deg[i] = 1.0f;   // self-loop contributes 1
}

__global__ void k_deg_scatter(const int* __restrict__ dst, float* deg) {
    int i = blockIdx.x * blockDim.x + threadIdx.x;
    if (i < N_EDGES) atomicAdd(&deg[dst[i]], 1.0f);
}

__global__ void k_rsqrt(float* deg) {
    int i = blockIdx.x * blockDim.x + threadIdx.x;
    if (i < N_NODES) deg[i] = rsqrtf(deg[i]);
}

// ---------------- dense node GEMM: out[n, :OUT_W] = h[n, :IN_W] @ W ----------------

template<int IN_W, int OUT_W>
__global__ void k_node_gemm(const float* __restrict__ h, const float* __restrict__ W,
                            float* __restrict__ out) {
    __shared__ float row[IN_W];
    int n = blockIdx.x;
    int j = threadIdx.x;             // blockDim.x == OUT_W
    if (j < IN_W) row[j] = h[n * IN_W + j];
    __syncthreads();
    float acc = 0.0f;
#pragma unroll
    for (int k = 0; k < IN_W; ++k) acc += row[k] * W[k * OUT_W + j];
    out[n * OUT_W + j] = acc;
}

// ---------------- agg init with bias ----------------

template<int W>
__global__ void k_fill_bias(float* __restrict__ agg, const float* __restrict__ b) {
    int t = blockIdx.x * blockDim.x + threadIdx.x;
    if (t < N_NODES * W) agg[t] = b[t & (W - 1)];
}

// ---------------- edge scatter: agg[dst] += h[src] * dinv[src]*dinv[dst] ----------------
// edges 0..N_EDGES-1 are real edges; N_EDGES..N_EDGES+N_NODES-1 are self-loops.

template<int W>
__global__ void k_scatter(const float* __restrict__ hw, const int* __restrict__ src,
                          const int* __restrict__ dst, const float* __restrict__ dinv,
                          float* agg) {
    const int EPB = 256 / W;
    int e = blockIdx.x * EPB + threadIdx.x / W;
    int j = threadIdx.x & (W - 1);
    const int total = N_EDGES + N_NODES;
    if (e >= total) return;
    int s, d;
    if (e < N_EDGES) { s = src[e]; d = dst[e]; }
    else             { s = d = e - N_EDGES; }
    float w = dinv[s] * dinv[d];
    atomicAdd(&agg[d * W + j], hw[s * W + j] * w);
}

// ---------------- relu ----------------

__global__ void k_relu(float* __restrict__ a, int n) {
    int i = blockIdx.x * blockDim.x + threadIdx.x;
    if (i < n) a[i] = fmaxf(a[i], 0.0f);
}

// ---------------- pooling ----------------

__global__ void k_pool_zero(float* pooled, float* cnts) {
    int i = blockIdx.x * blockDim.x + threadIdx.x;
    if (i < N_GRAPHS * 128) pooled[i] = 0.0f;
    if (i < N_GRAPHS) cnts[i] = 0.0f;
}

__global__ void k_pool_scatter(const float* __restrict__ h, const int* __restrict__ batch,
                               float* pooled, float* cnts) {
    int n = blockIdx.x;
    int j = threadIdx.x;             // 128
    int g = batch[n];
    atomicAdd(&pooled[g * 128 + j], h[n * 128 + j]);
    if (j == 0) atomicAdd(&cnts[g], 1.0f);
}

// ---------------- final FC head ----------------

__global__ void k_fc(const float* __restrict__ pooled, const float* __restrict__ cnts,
                     const float* __restrict__ Wf1, const float* __restrict__ bf1,
                     const float* __restrict__ Wf2, const float* __restrict__ bf2,
                     float* __restrict__ out) {
    __shared__ float sp[128];
    __shared__ float sh1[64];
    int g = blockIdx.x;
    int t = threadIdx.x;             // 128
    float inv = 1.0f / fmaxf(cnts[g], 1.0f);
    sp[t] = pooled[g * 128 + t] * inv;
    __syncthreads();
    if (t < 64) {
        float acc = bf1[t];
#pragma unroll 8
        for (int k = 0; k < 128; ++k) acc += sp[k] * Wf1[k * 64 + t];
        sh1[t] = fmaxf(acc, 0.0f);
    }
    __syncthreads();
    if (t < 10) {
        float acc = bf2[t];
#pragma unroll 8
        for (int k = 0; k < 64; ++k) acc += sh1[k] * Wf2[k * 10 + t];
        out[g * 10 + t] = acc;
    }
}

extern "C" void kernel_launch(void* const* d_in, const int* in_sizes, int n_in,
                              void* d_out, int out_size, void* d_ws, size_t ws_size,
                              hipStream_t stream) {
    const float* x     = (const float*)d_in[0];
    const int*   ei    = (const int*)d_in[1];
    const int*   batch = (const int*)d_in[2];
    const float* W1  = (const float*)d_in[3];
    const float* b1  = (const float*)d_in[4];
    const float* W2  = (const float*)d_in[5];
    const float* b2  = (const float*)d_in[6];
    const float* W3  = (const float*)d_in[7];
    const float* b3  = (const float*)d_in[8];
    const float* Wf1 = (const float*)d_in[9];
    const float* bf1 = (const float*)d_in[10];
    const float* Wf2 = (const float*)d_in[11];
    const float* bf2 = (const float*)d_in[12];
    float* out = (float*)d_out;

    const int* src = ei;              // edge_index[0]
    const int* dst = ei + N_EDGES;    // edge_index[1]

    // workspace layout (floats)
    float* deg    = (float*)d_ws;                 // N
    float* bufA   = deg + N_NODES;                // N*128
    float* bufB   = bufA + N_NODES * 128;         // N*128
    float* pooled = bufB + N_NODES * 128;         // G*128
    float* cnts   = pooled + N_GRAPHS * 128;      // G

    const int TB = 256;
    const int totE = N_EDGES + N_NODES;

    // degree + norm
    k_init_deg<<<(N_NODES + TB - 1) / TB, TB, 0, stream>>>(deg);
    k_deg_scatter<<<(N_EDGES + TB - 1) / TB, TB, 0, stream>>>(dst, deg);
    k_rsqrt<<<(N_NODES + TB - 1) / TB, TB, 0, stream>>>(deg);

    // ---- layer 1: 3 -> 64 ----
    k_node_gemm<3, 64><<<N_NODES, 64, 0, stream>>>(x, W1, bufA);
    k_fill_bias<64><<<(N_NODES * 64 + TB - 1) / TB, TB, 0, stream>>>(bufB, b1);
    k_scatter<64><<<(totE + 3) / 4, TB, 0, stream>>>(bufA, src, dst, deg, bufB);
    k_relu<<<(N_NODES * 64 + TB - 1) / TB, TB, 0, stream>>>(bufB, N_NODES * 64);

    // ---- layer 2: 64 -> 128 ----
    k_node_gemm<64, 128><<<N_NODES, 128, 0, stream>>>(bufB, W2, bufA);
    k_fill_bias<128><<<(N_NODES * 128 + TB - 1) / TB, TB, 0, stream>>>(bufB, b2);
    k_scatter<128><<<(totE + 1) / 2, TB, 0, stream>>>(bufA, src, dst, deg, bufB);
    k_relu<<<(N_NODES * 128 + TB - 1) / TB, TB, 0, stream>>>(bufB, N_NODES * 128);

    // ---- layer 3: 128 -> 128 ----
    k_node_gemm<128, 128><<<N_NODES, 128, 0, stream>>>(bufB, W3, bufA);
    k_fill_bias<128><<<(N_NODES * 128 + TB - 1) / TB, TB, 0, stream>>>(bufB, b3);
    k_scatter<128><<<(totE + 1) / 2, TB, 0, stream>>>(bufA, src, dst, deg, bufB);
    k_relu<<<(N_NODES * 128 + TB - 1) / TB, TB, 0, stream>>>(bufB, N_NODES * 128);

    // ---- global mean pool + FC head ----
    k_pool_zero<<<(N_GRAPHS * 128 + TB - 1) / TB, TB, 0, stream>>>(pooled, cnts);
    k_pool_scatter<<<N_NODES, 128, 0, stream>>>(bufB, batch, pooled, cnts);
    k_fc<<<N_GRAPHS, 128, 0, stream>>>(pooled, cnts, Wf1, bf1, Wf2, bf2, out);
}